// Round 3
// baseline (354.395 us; speedup 1.0000x reference)
//
#include <hip/hip_runtime.h>
#include <math.h>

#define EPS 1e-6f
#define CH_L 16   // tokens per chunk (4 waves x 4 tokens, stride-4 interleave)
// Problem constants: D = 1024 (= 256 float4 = blockDim), S = 4096, B = 16.

__device__ __forceinline__ float4 sigmoid4(float4 lg) {
    return make_float4(1.f / (1.f + expf(-lg.x)), 1.f / (1.f + expf(-lg.y)),
                       1.f / (1.f + expf(-lg.z)), 1.f / (1.f + expf(-lg.w)));
}

// Block-wide window length K s.t. max(decay)^K < 1e-12 (clamped to S).
// All 256 threads must call; contains one __syncthreads.
__device__ __forceinline__ int window_K(float4 dec, int S, int tid, float* red) {
    int wv = tid >> 6, ln = tid & 63;
    float m = fmaxf(fmaxf(dec.x, dec.y), fmaxf(dec.z, dec.w));
    for (int off = 32; off; off >>= 1) m = fmaxf(m, __shfl_xor(m, off));
    if (ln == 0) red[wv] = m;
    __syncthreads();
    float maxd = fmaxf(fmaxf(red[0], red[1]), fmaxf(red[2], red[3]));
    float Kf;
    if (maxd <= 0.f) Kf = 1.f;
    else {
        float lgm = logf(maxd);
        Kf = (lgm >= 0.f) ? (float)S : (logf(1e-12f) / lgm);
    }
    return (Kf >= (float)S) ? S : ((int)Kf + 1);
}

// ---------------------------------------------------------------------------
// k_ema: fused decay-prep + rmsnorm + per-chunk EMA partial. Grid-stride over
// active (b,c) pairs; chunk c = tokens [S-(c+1)*16, S-c*16). Wave w handles
// tokens t0+4j+w; a wave holds a full token (64 lanes x 16 floats = D), so
// sum-of-squares is a wave butterfly. Exact decomposition: per-token coef
// cw*dec^(3-w), step multiplier dec^4, partial = sum over waves; final
// state = sum_c partial_c * dec^(16c).
// ---------------------------------------------------------------------------
__global__ void k_ema(const float4* __restrict__ x4, const float4* __restrict__ logit4,
                      const float4* __restrict__ w14, float4* __restrict__ partial4,
                      int B, int S, int nchunk) {
    __shared__ float4 sdec[256], scw[256];
    __shared__ float red[4];
    __shared__ float4 sm[4][256];
    int tid = threadIdx.x, wv = tid >> 6, ln = tid & 63;

    float4 dec_t = sigmoid4(logit4[tid]);
    float4 w1 = w14[tid];
    sdec[tid] = dec_t;
    scw[tid] = make_float4((1.f - dec_t.x) * w1.x, (1.f - dec_t.y) * w1.y,
                           (1.f - dec_t.z) * w1.z, (1.f - dec_t.w) * w1.w);
    int K = window_K(dec_t, S, tid, red);   // barrier also publishes sdec/scw

    float4 d4p[4], cwp[4];
#pragma unroll
    for (int k = 0; k < 4; k++) {
        float4 d = sdec[k * 64 + ln];
        float4 cw = scw[k * 64 + ln];
        float4 d2 = make_float4(d.x * d.x, d.y * d.y, d.z * d.z, d.w * d.w);
        d4p[k] = make_float4(d2.x * d2.x, d2.y * d2.y, d2.z * d2.z, d2.w * d2.w);
        float4 pw;   // dec^(3-wv)
        if (wv == 3)      pw = make_float4(1.f, 1.f, 1.f, 1.f);
        else if (wv == 2) pw = d;
        else if (wv == 1) pw = d2;
        else              pw = make_float4(d2.x * d.x, d2.y * d.y, d2.z * d.z, d2.w * d.w);
        cwp[k] = make_float4(cw.x * pw.x, cw.y * pw.y, cw.z * pw.z, cw.w * pw.w);
    }

    int nact = K / CH_L + 1; if (nact > nchunk) nact = nchunk;
    int total = B * nact;
    for (int i = blockIdx.x; i < total; i += gridDim.x) {
        int b = i / nact, c = i % nact;
        float4 acc[4];
#pragma unroll
        for (int k = 0; k < 4; k++) acc[k] = make_float4(0.f, 0.f, 0.f, 0.f);
        int t0 = S - (c + 1) * CH_L;
#pragma unroll
        for (int j = 0; j < 4; j++) {
            int t = t0 + 4 * j + wv;
            const float4* xp = x4 + ((size_t)b * S + t) * 256;
            float4 xv[4];
#pragma unroll
            for (int k = 0; k < 4; k++) xv[k] = xp[k * 64 + ln];
            float s = 0.f;
#pragma unroll
            for (int k = 0; k < 4; k++)
                s += xv[k].x * xv[k].x + xv[k].y * xv[k].y + xv[k].z * xv[k].z + xv[k].w * xv[k].w;
            for (int m = 1; m < 64; m <<= 1) s += __shfl_xor(s, m);
            float ir = rsqrtf(s * (1.f / 1024.f) + EPS);
#pragma unroll
            for (int k = 0; k < 4; k++) {
                acc[k].x = acc[k].x * d4p[k].x + xv[k].x * (cwp[k].x * ir);
                acc[k].y = acc[k].y * d4p[k].y + xv[k].y * (cwp[k].y * ir);
                acc[k].z = acc[k].z * d4p[k].z + xv[k].z * (cwp[k].z * ir);
                acc[k].w = acc[k].w * d4p[k].w + xv[k].w * (cwp[k].w * ir);
            }
        }
        __syncthreads();   // protect sm across grid-stride iterations
#pragma unroll
        for (int k = 0; k < 4; k++) sm[wv][k * 64 + ln] = acc[k];
        __syncthreads();
        float4 r0 = sm[0][tid], r1 = sm[1][tid], r2 = sm[2][tid], r3 = sm[3][tid];
        partial4[((size_t)b * nchunk + c) * 256 + tid] =
            make_float4(r0.x + r1.x + r2.x + r3.x, r0.y + r1.y + r2.y + r3.y,
                        r0.z + r1.z + r2.z + r3.z, r0.w + r1.w + r2.w + r3.w);
    }
}

// ---------------------------------------------------------------------------
// k_pool: fused decay-prep + combine chunk partials (running dec^16 weight),
// residual add x[:,S-1,:], rmsnorm2 -> pool[b,:]. One block per b.
// ---------------------------------------------------------------------------
__global__ void k_pool(const float4* __restrict__ x4, const float4* __restrict__ logit4,
                       const float4* __restrict__ w24, const float4* __restrict__ partial4,
                       float4* __restrict__ pool4, int S, int nchunk) {
    __shared__ float red[4];
    __shared__ float tot;
    int b = blockIdx.x;
    int tid = threadIdx.x, wv = tid >> 6, ln = tid & 63;
    float4 d = sigmoid4(logit4[tid]);
    int K = window_K(d, S, tid, red);
    int cmax = K / CH_L; if (cmax > nchunk - 1) cmax = nchunk - 1;
    float4 d2 = make_float4(d.x * d.x, d.y * d.y, d.z * d.z, d.w * d.w);
    float4 d4 = make_float4(d2.x * d2.x, d2.y * d2.y, d2.z * d2.z, d2.w * d2.w);
    float4 d8 = make_float4(d4.x * d4.x, d4.y * d4.y, d4.z * d4.z, d4.w * d4.w);
    float4 dL = make_float4(d8.x * d8.x, d8.y * d8.y, d8.z * d8.z, d8.w * d8.w);
    float4 st = make_float4(0.f, 0.f, 0.f, 0.f);
    float4 wgt = make_float4(1.f, 1.f, 1.f, 1.f);
    for (int c = 0; c <= cmax; c++) {
        float4 p = partial4[((size_t)b * nchunk + c) * 256 + tid];
        st.x += p.x * wgt.x; st.y += p.y * wgt.y;
        st.z += p.z * wgt.z; st.w += p.w * wgt.w;
        wgt.x *= dL.x; wgt.y *= dL.y; wgt.z *= dL.z; wgt.w *= dL.w;
    }
    float4 xl = x4[((size_t)b * S + (S - 1)) * 256 + tid];
    float4 y = make_float4(xl.x + st.x, xl.y + st.y, xl.z + st.z, xl.w + st.w);
    float ss = y.x * y.x + y.y * y.y + y.z * y.z + y.w * y.w;
    for (int m = 1; m < 64; m <<= 1) ss += __shfl_xor(ss, m);
    __syncthreads();   // red was used inside window_K; re-protect
    if (ln == 0) red[wv] = ss;
    __syncthreads();
    if (tid == 0) tot = red[0] + red[1] + red[2] + red[3];
    __syncthreads();
    float ir = rsqrtf(tot * (1.f / 1024.f) + EPS);
    float4 w2 = w24[tid];
    pool4[(size_t)b * 256 + tid] = make_float4(y.x * ir * w2.x, y.y * ir * w2.y,
                                               y.z * ir * w2.z, y.w * ir * w2.w);
}

// ---------------------------------------------------------------------------
// k_matmul: expert-grouped. Grid (O/64 tiles, n_experts). Block stages the
// pool vectors of all b's with its expert in LDS, reads each W row ONCE
// (4x float4 per lane), and dots against every matching b.
// ---------------------------------------------------------------------------
__global__ void k_matmul(const float* __restrict__ pool, const float* __restrict__ W,
                         const int* __restrict__ experts, float* __restrict__ out,
                         int B, int D, int O) {
    __shared__ float4 sp[16][256];   // staged pools (<= 16 b's)
    __shared__ int blist[16];
    __shared__ int snb;
    int e = blockIdx.y;
    int o0 = blockIdx.x * 64;
    int tid = threadIdx.x, wv = tid >> 6, ln = tid & 63;
    if (tid == 0) {
        int nb = 0;
        for (int b = 0; b < B; b++) if (experts[b] == e) blist[nb++] = b;
        snb = nb;
    }
    __syncthreads();
    int nb = snb;
    if (nb == 0) return;
    const float4* pool4 = (const float4*)pool;
    for (int j = 0; j < nb; j++) sp[j][tid] = pool4[(size_t)blist[j] * 256 + tid];
    __syncthreads();
    const float4* Wb = (const float4*)W + (size_t)e * O * 256;
#pragma unroll 4
    for (int rr = 0; rr < 16; rr++) {
        int row = o0 + wv * 16 + rr;
        float4 w4[4];
#pragma unroll
        for (int k = 0; k < 4; k++) w4[k] = Wb[(size_t)row * 256 + k * 64 + ln];
        for (int j = 0; j < nb; j++) {
            float s = 0.f;
#pragma unroll
            for (int k = 0; k < 4; k++) {
                float4 p = sp[j][k * 64 + ln];
                s += w4[k].x * p.x + w4[k].y * p.y + w4[k].z * p.z + w4[k].w * p.w;
            }
            for (int off = 32; off; off >>= 1) s += __shfl_down(s, off);
            if (ln == 0) out[(size_t)blist[j] * O + row] = fmaxf(s, 0.f);
        }
    }
}

// ---------------------------------------------------------------------------
extern "C" void kernel_launch(void* const* d_in, const int* in_sizes, int n_in,
                              void* d_out, int out_size, void* d_ws, size_t ws_size,
                              hipStream_t stream) {
    const float* x       = (const float*)d_in[0];
    const int*   experts = (const int*)  d_in[1];
    const float* w1      = (const float*)d_in[2];
    const float* logit   = (const float*)d_in[3];
    const float* w2      = (const float*)d_in[4];
    const float* W       = (const float*)d_in[5];
    float* out = (float*)d_out;

    int B  = in_sizes[1];
    int D  = in_sizes[2];            // 1024
    int S  = in_sizes[0] / (B * D);  // 4096
    int O  = D;
    int NE = in_sizes[5] / (D * D);  // 4
    int nchunk = S / CH_L;           // 256

    float* ws      = (float*)d_ws;
    float* partial = ws;                                 // B*nchunk*D floats
    float* pool    = partial + (size_t)B * nchunk * D;   // B*D floats

    k_ema<<<512, 256, 0, stream>>>((const float4*)x, (const float4*)logit,
                                   (const float4*)w1, (float4*)partial, B, S, nchunk);
    k_pool<<<B, 256, 0, stream>>>((const float4*)x, (const float4*)logit,
                                  (const float4*)w2, (const float4*)partial,
                                  (float4*)pool, S, nchunk);
    k_matmul<<<dim3(O / 64, NE), 256, 0, stream>>>(pool, W, experts, out, B, D, O);
}

// Round 4
// 346.253 us; speedup vs baseline: 1.0235x; 1.0235x over previous
//
#include <hip/hip_runtime.h>
#include <math.h>

#define EPS 1e-6f
#define CH_L 16   // tokens per chunk (4 waves x 4 tokens, stride-4 interleave)
// Problem constants: D = 1024 (= 256 float4 = blockDim), S = 4096, B = 16, NE = 4.

// ---------------------------------------------------------------------------
// k_prep: decay = sigmoid(logit); cw = (1-decay)*w1; dL = decay^16;
// nact = number of active 16-token chunks so that truncation error < 1e-12
// of state magnitude (clamped to nchunk). One block, 256 threads.
// ---------------------------------------------------------------------------
__global__ void k_prep(const float4* __restrict__ logit4, const float4* __restrict__ w14,
                       float4* __restrict__ decay4, float4* __restrict__ cw4,
                       float4* __restrict__ dL4, int* __restrict__ nactp,
                       int S, int nchunk) {
    int tid = threadIdx.x, wv = tid >> 6, ln = tid & 63;
    float4 lg = logit4[tid];
    float4 w1 = w14[tid];
    float4 d;
    d.x = 1.f / (1.f + expf(-lg.x));
    d.y = 1.f / (1.f + expf(-lg.y));
    d.z = 1.f / (1.f + expf(-lg.z));
    d.w = 1.f / (1.f + expf(-lg.w));
    decay4[tid] = d;
    cw4[tid] = make_float4((1.f - d.x) * w1.x, (1.f - d.y) * w1.y,
                           (1.f - d.z) * w1.z, (1.f - d.w) * w1.w);
    float4 d2 = make_float4(d.x * d.x, d.y * d.y, d.z * d.z, d.w * d.w);
    float4 d4 = make_float4(d2.x * d2.x, d2.y * d2.y, d2.z * d2.z, d2.w * d2.w);
    float4 d8 = make_float4(d4.x * d4.x, d4.y * d4.y, d4.z * d4.z, d4.w * d4.w);
    dL4[tid] = make_float4(d8.x * d8.x, d8.y * d8.y, d8.z * d8.z, d8.w * d8.w);
    float m = fmaxf(fmaxf(d.x, d.y), fmaxf(d.z, d.w));
    for (int off = 32; off; off >>= 1) m = fmaxf(m, __shfl_xor(m, off));
    __shared__ float red[4];
    if (ln == 0) red[wv] = m;
    __syncthreads();
    if (tid == 0) {
        float maxd = fmaxf(fmaxf(red[0], red[1]), fmaxf(red[2], red[3]));
        float Kf;
        if (maxd <= 0.f) Kf = 1.f;
        else {
            float lgm = logf(maxd);
            Kf = (lgm >= 0.f) ? (float)S : (logf(1e-12f) / lgm);
        }
        int K = (Kf >= (float)S) ? S : ((int)Kf + 1);
        int na = K / CH_L + 1;
        if (na > nchunk) na = nchunk;
        *nactp = na;
    }
}

// ---------------------------------------------------------------------------
// k_ema: fused rmsnorm1 + per-chunk EMA partial. Grid (nchunk, B); blocks
// with c >= nact exit on a single scalar load. Chunk c = tokens
// [S-(c+1)*16, S-c*16). Wave w handles tokens t0+4j+w; one wave holds a
// full token (64 lanes x 16 floats = D) so sum-of-squares is a wave
// butterfly. Exact decomposition: per-token coef cw*dec^(3-w), step
// multiplier dec^4; partial_c = sum over waves; state = sum_c partial_c *
// dec^(16c).
// ---------------------------------------------------------------------------
__global__ void k_ema(const float4* __restrict__ x4, const float4* __restrict__ decay4,
                      const float4* __restrict__ cw4, const int* __restrict__ nactp,
                      float4* __restrict__ partial4, int S, int nchunk) {
    int c = blockIdx.x, b = blockIdx.y;
    if (c >= *nactp) return;
    int tid = threadIdx.x, wv = tid >> 6, ln = tid & 63;

    float4 d4p[4], cwp[4];
#pragma unroll
    for (int k = 0; k < 4; k++) {
        float4 d = decay4[k * 64 + ln];
        float4 cw = cw4[k * 64 + ln];
        float4 d2 = make_float4(d.x * d.x, d.y * d.y, d.z * d.z, d.w * d.w);
        d4p[k] = make_float4(d2.x * d2.x, d2.y * d2.y, d2.z * d2.z, d2.w * d2.w);
        float4 pw;   // dec^(3-wv)
        if (wv == 3)      pw = make_float4(1.f, 1.f, 1.f, 1.f);
        else if (wv == 2) pw = d;
        else if (wv == 1) pw = d2;
        else              pw = make_float4(d2.x * d.x, d2.y * d.y, d2.z * d.z, d2.w * d.w);
        cwp[k] = make_float4(cw.x * pw.x, cw.y * pw.y, cw.z * pw.z, cw.w * pw.w);
    }

    float4 acc[4];
#pragma unroll
    for (int k = 0; k < 4; k++) acc[k] = make_float4(0.f, 0.f, 0.f, 0.f);
    int t0 = S - (c + 1) * CH_L;
#pragma unroll
    for (int j = 0; j < 4; j++) {
        int t = t0 + 4 * j + wv;
        const float4* xp = x4 + ((size_t)b * S + t) * 256;
        float4 xv[4];
#pragma unroll
        for (int k = 0; k < 4; k++) xv[k] = xp[k * 64 + ln];
        float s = 0.f;
#pragma unroll
        for (int k = 0; k < 4; k++)
            s += xv[k].x * xv[k].x + xv[k].y * xv[k].y + xv[k].z * xv[k].z + xv[k].w * xv[k].w;
        for (int m = 1; m < 64; m <<= 1) s += __shfl_xor(s, m);
        float ir = rsqrtf(s * (1.f / 1024.f) + EPS);
#pragma unroll
        for (int k = 0; k < 4; k++) {
            acc[k].x = acc[k].x * d4p[k].x + xv[k].x * (cwp[k].x * ir);
            acc[k].y = acc[k].y * d4p[k].y + xv[k].y * (cwp[k].y * ir);
            acc[k].z = acc[k].z * d4p[k].z + xv[k].z * (cwp[k].z * ir);
            acc[k].w = acc[k].w * d4p[k].w + xv[k].w * (cwp[k].w * ir);
        }
    }

    __shared__ float4 sm[4][256];
#pragma unroll
    for (int k = 0; k < 4; k++) sm[wv][k * 64 + ln] = acc[k];
    __syncthreads();
    float4 r0 = sm[0][tid], r1 = sm[1][tid], r2 = sm[2][tid], r3 = sm[3][tid];
    partial4[((size_t)b * nchunk + c) * 256 + tid] =
        make_float4(r0.x + r1.x + r2.x + r3.x, r0.y + r1.y + r2.y + r3.y,
                    r0.z + r1.z + r2.z + r3.z, r0.w + r1.w + r2.w + r3.w);
}

// ---------------------------------------------------------------------------
// k_poolmm: fused pool + expert matmul. Grid (O/16, NE). Each block:
// builds the list of b's assigned its expert, recomputes their pool
// vectors from chunk partials (combine with running dec^16 weight, residual
// add x[:,S-1,:], rmsnorm2) into LDS, then reads its 16 W rows once and
// dots against every staged pool. Pool recompute is redundant across the
// 64 o-tiles of an expert but entirely L2-hot (~56 KB/b).
// ---------------------------------------------------------------------------
__global__ void k_poolmm(const float4* __restrict__ x4, const float4* __restrict__ partial4,
                         const float4* __restrict__ decay16_4, const float4* __restrict__ w24,
                         const int* __restrict__ nactp, const float* __restrict__ W,
                         const int* __restrict__ experts, float* __restrict__ out,
                         int B, int S, int nchunk, int O) {
    __shared__ float4 sp[16][256];
    __shared__ int blist[16];
    __shared__ int snb;
    __shared__ float red[4];
    __shared__ float tot;
    int e = blockIdx.y;
    int o0 = blockIdx.x * 16;
    int tid = threadIdx.x, wv = tid >> 6, ln = tid & 63;
    if (tid == 0) {
        int nb = 0;
        for (int b = 0; b < B; b++) if (experts[b] == e) blist[nb++] = b;
        snb = nb;
    }
    __syncthreads();
    int nb = snb;
    if (nb == 0) return;

    int cmax = *nactp - 1;
    if (cmax > nchunk - 1) cmax = nchunk - 1;
    float4 dL = decay16_4[tid];
    float4 w2 = w24[tid];

    for (int j = 0; j < nb; j++) {
        int b = blist[j];
        float4 st = make_float4(0.f, 0.f, 0.f, 0.f);
        float4 wgt = make_float4(1.f, 1.f, 1.f, 1.f);
        const float4* pp = partial4 + (size_t)b * nchunk * 256 + tid;
        for (int c = 0; c <= cmax; c++) {
            float4 p = pp[(size_t)c * 256];
            st.x += p.x * wgt.x; st.y += p.y * wgt.y;
            st.z += p.z * wgt.z; st.w += p.w * wgt.w;
            wgt.x *= dL.x; wgt.y *= dL.y; wgt.z *= dL.z; wgt.w *= dL.w;
        }
        float4 xl = x4[((size_t)b * S + (S - 1)) * 256 + tid];
        float4 y = make_float4(xl.x + st.x, xl.y + st.y, xl.z + st.z, xl.w + st.w);
        float ss = y.x * y.x + y.y * y.y + y.z * y.z + y.w * y.w;
        for (int m = 1; m < 64; m <<= 1) ss += __shfl_xor(ss, m);
        if (ln == 0) red[wv] = ss;
        __syncthreads();
        if (tid == 0) tot = red[0] + red[1] + red[2] + red[3];
        __syncthreads();
        float ir = rsqrtf(tot * (1.f / 1024.f) + EPS);
        sp[j][tid] = make_float4(y.x * ir * w2.x, y.y * ir * w2.y,
                                 y.z * ir * w2.z, y.w * ir * w2.w);
        __syncthreads();   // red/tot reused next j; sp[j] published
    }

    const float4* Wb = (const float4*)W + (size_t)e * O * 256;
#pragma unroll 4
    for (int rr = 0; rr < 4; rr++) {
        int row = o0 + wv * 4 + rr;
        float4 w4[4];
#pragma unroll
        for (int k = 0; k < 4; k++) w4[k] = Wb[(size_t)row * 256 + k * 64 + ln];
        for (int j = 0; j < nb; j++) {
            float s = 0.f;
#pragma unroll
            for (int k = 0; k < 4; k++) {
                float4 p = sp[j][k * 64 + ln];
                s += w4[k].x * p.x + w4[k].y * p.y + w4[k].z * p.z + w4[k].w * p.w;
            }
            for (int off = 32; off; off >>= 1) s += __shfl_down(s, off);
            if (ln == 0) out[(size_t)blist[j] * O + row] = fmaxf(s, 0.f);
        }
    }
}

// ---------------------------------------------------------------------------
extern "C" void kernel_launch(void* const* d_in, const int* in_sizes, int n_in,
                              void* d_out, int out_size, void* d_ws, size_t ws_size,
                              hipStream_t stream) {
    const float* x       = (const float*)d_in[0];
    const int*   experts = (const int*)  d_in[1];
    const float* w1      = (const float*)d_in[2];
    const float* logit   = (const float*)d_in[3];
    const float* w2      = (const float*)d_in[4];
    const float* W       = (const float*)d_in[5];
    float* out = (float*)d_out;

    int B  = in_sizes[1];
    int D  = in_sizes[2];            // 1024
    int S  = in_sizes[0] / (B * D);  // 4096
    int O  = D;
    int NE = in_sizes[5] / (D * D);  // 4
    int nchunk = S / CH_L;           // 256

    float* ws      = (float*)d_ws;
    float* decay   = ws;                        // D floats
    float* cw      = ws + D;                    // D floats
    float* dL      = ws + 2 * D;                // D floats (decay^16)
    int*   nactp   = (int*)(ws + 3 * D);        // 1 int (64-float pad)
    float* partial = ws + 3 * D + 64;           // B*nchunk*D floats

    k_prep<<<1, 256, 0, stream>>>((const float4*)logit, (const float4*)w1,
                                  (float4*)decay, (float4*)cw, (float4*)dL,
                                  nactp, S, nchunk);
    k_ema<<<dim3(nchunk, B), 256, 0, stream>>>((const float4*)x, (const float4*)decay,
                                               (const float4*)cw, nactp,
                                               (float4*)partial, S, nchunk);
    k_poolmm<<<dim3(O / 16, NE), 256, 0, stream>>>((const float4*)x, (const float4*)partial,
                                                   (const float4*)dL, (const float4*)w2,
                                                   nactp, W, experts, out,
                                                   B, S, nchunk, O);
}